// Round 4
// baseline (290.922 us; speedup 1.0000x reference)
//
#include <hip/hip_runtime.h>

#define C_IN  128
#define C_RES 64
#define D     512
#define DD    (D * D)          // 262144 floats per c-slice
#define NC4   (DD / 4)         // 65536 float4 chunks per (o,i) plane

// Column-sum of 64 c-slices at 1 MB stride.
__device__ __forceinline__ float4 colsum64(const float4* __restrict__ p) {
    float4 acc = make_float4(0.f, 0.f, 0.f, 0.f);
#pragma unroll 16
    for (int c = 0; c < 64; ++c) {
        float4 w = p[(size_t)c * NC4];
        acc.x += w.x; acc.y += w.y; acc.z += w.z; acc.w += w.w;
    }
    return acc;
}

// ---------------------------------------------------------------------------
// K1: 384 blocks x 256 = 98304 threads, two balanced 64-deep colsum jobs each
// (round-1 mapping: full S2 coverage, every thread exactly 128 float4 loads).
//   S1lo = sum W1 c[0,64), S1hi = sum W1 c[64,128), S2 = sum W2.
// Also: zero diff1 and init out = relu(x) + bc2 (the K4 epilogue constant),
// so the tail kernel can atomically accumulate straight into out.
// NOTE: duration is pinned by a concurrent harness poison-fill (~77 us at
// 6.9 TB/s); K1 rides the leftover ~1.5 TB/s. Occupancy tuning is a dead
// lever here (measured rounds 0/2/3 identical).
// ---------------------------------------------------------------------------
__global__ __launch_bounds__(256)
void sum_init_kernel(const float* __restrict__ W1,
                     const float* __restrict__ W2,
                     const float* __restrict__ x,
                     const float* __restrict__ bc2,
                     float* __restrict__ S1lo,
                     float* __restrict__ S1hi,
                     float* __restrict__ S2,
                     float* __restrict__ diff1,
                     float* __restrict__ out) {
    const int u = blockIdx.x * 256 + threadIdx.x;     // 0 .. 98303
    // job A: W1 low channels (full plane) + W1 high channels (first half)
    if (u < NC4) {
        ((float4*)S1lo)[u] = colsum64((const float4*)W1 + u);
    } else {
        int t = u - NC4;                              // 0..32767
        ((float4*)S1hi)[t] = colsum64((const float4*)W1 + (size_t)64 * NC4 + t);
    }
    // job B: W1 high channels (second half) + W2 (full plane)
    if (u < NC4 / 2) {
        int t = u + NC4 / 2;                          // 32768..65535
        ((float4*)S1hi)[t] = colsum64((const float4*)W1 + (size_t)64 * NC4 + t);
    } else {
        int t = u - NC4 / 2;                          // 0..65535
        ((float4*)S2)[t] = colsum64((const float4*)W2 + t);
    }
    if (u < C_IN * D) {
        diff1[u] = 0.f;
        out[u] = fmaxf(x[u], 0.f) + bc2[u >> 9];      // residual + stage-2 bias
    }
}

// ---------------------------------------------------------------------------
// K2: 64 blocks x 256 (round-0 shape). Blocks 0..31: stage-1 argmax over
// S1lo+S1hi for 16 columns, then scatter diff1[c,n] += W1[c,n,i]*relu(x[c,i]).
// Blocks 32..63: stage-2 argmax over S2 -> node2, pre-gather w2v = W2[c,n_i,i].
// Tie-break = first (smallest o), matching jnp.argmax.
// ---------------------------------------------------------------------------
__global__ __launch_bounds__(256)
void argmax_scatter_kernel(const float* __restrict__ S1lo,
                           const float* __restrict__ S1hi,
                           const float* __restrict__ S2,
                           const float* __restrict__ W1,
                           const float* __restrict__ W2,
                           const float* __restrict__ x,
                           float* __restrict__ diff1,
                           float* __restrict__ w2v,
                           int* __restrict__ node2) {
    __shared__ float lv[256];
    __shared__ int   li[256];
    __shared__ int   node_s[16];

    const int  tid = threadIdx.x;
    const bool st1 = blockIdx.x < 32;
    const int  i0  = (blockIdx.x & 31) * 16;
    const int  il  = tid & 15;
    const int  ol  = tid >> 4;                        // 0..15

    float best = -__builtin_inff();
    int   bidx = D;                                   // > any valid o
#pragma unroll 4
    for (int k = 0; k < 32; ++k) {
        int o   = ol + (k << 4);                      // ascending per thread
        int off = o * D + i0 + il;
        float v = st1 ? (S1lo[off] + S1hi[off]) : S2[off];
        if (v > best) { best = v; bidx = o; }         // strict >: first wins
    }
    lv[tid] = best; li[tid] = bidx;
    __syncthreads();
    for (int s = 128; s >= 16; s >>= 1) {
        if (tid < s) {
            float v2 = lv[tid + s]; int i2 = li[tid + s];
            if (v2 > lv[tid] || (v2 == lv[tid] && i2 < li[tid])) {
                lv[tid] = v2; li[tid] = i2;
            }
        }
        __syncthreads();
    }
    if (tid < 16) {
        node_s[tid] = li[tid];
        if (!st1) node2[i0 + tid] = li[tid];
    }
    __syncthreads();

    if (st1) {
        for (int idx = tid; idx < C_IN * 16; idx += 256) {
            int ii = idx & 15;
            int c  = idx >> 4;
            int i  = i0 + ii;
            int n  = node_s[ii];
            float xv = fmaxf(x[c * D + i], 0.f);
            float w  = W1[(size_t)c * DD + (size_t)n * D + i];
            atomicAdd(&diff1[c * D + n], w * xv);
        }
    } else {
        for (int idx = tid; idx < C_RES * 16; idx += 256) {
            int ii = idx & 15;
            int c  = idx >> 4;
            int i  = i0 + ii;
            int n  = node_s[ii];
            w2v[c * D + i] = W2[(size_t)c * DD + (size_t)n * D + i];
        }
    }
}

// ---------------------------------------------------------------------------
// K3 (fused former K3+K4): per 8-column block,
//   x2[c,i] = relu(bc1[c] + sum_cc Wc1[c,cc]*diff1[cc,i])
//   t[c,i]  = w2v[c,i] * x2[c,i]
//   z[o,i]  = sum_c Wc2[o,c] * t[c,i]
//   atomicAdd(out[o, node2[i]], z[o,i])     (out pre-init'd = relu(x)+bc2)
// diff2 never materializes: saves a dispatch, its zeroing, and a round-trip.
// 64 blocks x 256.
// ---------------------------------------------------------------------------
__global__ __launch_bounds__(256)
void tail_kernel(const float* __restrict__ Wc1,
                 const float* __restrict__ bc1,
                 const float* __restrict__ diff1,
                 const float* __restrict__ w2v,
                 const int* __restrict__ node2,
                 const float* __restrict__ Wc2,
                 float* __restrict__ out) {
    __shared__ float wc1s[C_RES][C_IN + 1];   // +1 pad: 2 lanes/bank on reads
    __shared__ float d1s[C_IN][8];
    __shared__ float ts[C_RES][9];            // +1 pad
    __shared__ int   nds[8];

    const int tid = threadIdx.x;
    const int i0  = blockIdx.x * 8;

    for (int idx = tid; idx < C_RES * C_IN; idx += 256)
        wc1s[idx >> 7][idx & 127] = Wc1[idx];
    for (int idx = tid; idx < C_IN * 8; idx += 256)
        d1s[idx >> 3][idx & 7] = diff1[(idx >> 3) * D + i0 + (idx & 7)];
    if (tid < 8) nds[tid] = node2[i0 + tid];
    __syncthreads();

    // Phase A: x2 & t. Thread (c = tid&63, j = tid>>6) handles i = 2j, 2j+1.
    {
        const int c = tid & 63;
        const int j = tid >> 6;                       // 0..3
        float a0 = bc1[c];
        float a1 = a0;
#pragma unroll 8
        for (int cc = 0; cc < C_IN; ++cc) {
            float w = wc1s[c][cc];                    // bank-friendly (pad)
            a0 += w * d1s[cc][2 * j];                 // broadcast across wave
            a1 += w * d1s[cc][2 * j + 1];
        }
        ts[c][2 * j]     = w2v[c * D + i0 + 2 * j]     * fmaxf(a0, 0.f);
        ts[c][2 * j + 1] = w2v[c * D + i0 + 2 * j + 1] * fmaxf(a1, 0.f);
    }
    __syncthreads();

    // Phase B: z + scatter. Thread (o = tid>>1, h = tid&1) handles i = 4h..4h+3.
    {
        const int o = tid >> 1;                       // 0..127
        const int h = tid & 1;
        float z0 = 0.f, z1 = 0.f, z2 = 0.f, z3 = 0.f;
#pragma unroll 8
        for (int c = 0; c < C_RES; ++c) {
            float w = Wc2[o * C_RES + c];
            z0 += w * ts[c][4 * h];
            z1 += w * ts[c][4 * h + 1];
            z2 += w * ts[c][4 * h + 2];
            z3 += w * ts[c][4 * h + 3];
        }
        atomicAdd(&out[o * D + nds[4 * h]],     z0);
        atomicAdd(&out[o * D + nds[4 * h + 1]], z1);
        atomicAdd(&out[o * D + nds[4 * h + 2]], z2);
        atomicAdd(&out[o * D + nds[4 * h + 3]], z3);
    }
}

extern "C" void kernel_launch(void* const* d_in, const int* in_sizes, int n_in,
                              void* d_out, int out_size, void* d_ws, size_t ws_size,
                              hipStream_t stream) {
    const float* x   = (const float*)d_in[0];   // (1, 128, 512)
    const float* W1  = (const float*)d_in[1];   // (128, 512, 512)
    const float* Wc1 = (const float*)d_in[2];   // (64, 128)
    const float* bc1 = (const float*)d_in[3];   // (64,)
    const float* W2  = (const float*)d_in[4];   // (64, 512, 512)
    const float* Wc2 = (const float*)d_in[5];   // (128, 64)
    const float* bc2 = (const float*)d_in[6];   // (128,)
    float* out = (float*)d_out;                 // (1, 128, 512) fp32

    float* ws    = (float*)d_ws;
    float* S1lo  = ws;                          // 262144
    float* S1hi  = S1lo + DD;                   // 262144
    float* S2    = S1hi + DD;                   // 262144
    float* diff1 = S2 + DD;                     // 65536
    float* w2v   = diff1 + C_IN * D;            // 32768
    int*   node2 = (int*)(w2v + C_RES * D);     // 512

    // K1: stream W1+W2 (201 MB) -> S planes; zero diff1; out = relu(x)+bc2
    sum_init_kernel<<<384, 256, 0, stream>>>(W1, W2, x, bc2,
                                             S1lo, S1hi, S2, diff1, out);
    // K2: argmax both stages + stage-1 scatter + stage-2 W-gather
    argmax_scatter_kernel<<<64, 256, 0, stream>>>(S1lo, S1hi, S2, W1, W2, x,
                                                  diff1, w2v, node2);
    // K3: conv1(+bias,relu) -> t -> conv2 -> scatter-add into pre-init'd out
    tail_kernel<<<64, 256, 0, stream>>>(Wc1, bc1, diff1, w2v, node2, Wc2, out);
}